// Round 2
// baseline (1733.369 us; speedup 1.0000x reference)
//
#include <hip/hip_runtime.h>
#include <hip/hip_bf16.h>

// USM sharpen, 48 images of 512x512 f32, 51-tap separable Gaussian, reflect pad.
// All four passes use ONE kernel shape: coalesced loads along the fast dim,
// register sliding-window blur along the slow dim, then an LDS 64x128 tile
// transpose so the next pass is again "vertical". Layouts:
//   pass1: img[y][x]      --vblur--> tmp[x][y]          (transposed)
//   pass2: tmp[x][y]      --xblur--> out[y][x] = img - blur   (residual)
//   pass3: out[y][x] mask --vblur--> tmp[x][y]
//   pass4: tmp[x][y]      --xblur--> out[y][x] = sm*sharp+(1-sm)*img (in-place)

constexpr int IMG = 512;
constexpr int NIMG = 48;
constexpr int K = 51, P = 25;
constexpr int CB = 64;              // columns (fast dim) per block = lanes
constexpr int RB = 128;             // rows (slow dim) per block
constexpr int VB = 32;              // rows per thread (RB / 4 waves)
constexpr int NLOOP = VB + K - 1;   // 82 sliding loads per thread
constexpr int LDS_R = RB + 1;       // stride 129 -> conflict-free both ways

// LOADM: 0 = raw, 1 = mask(|v|*255 > 10)
// STOREM: 0 = blur -> dst (transposed tile)
//         1 = img - blur -> dst (residual)
//         2 = sm=blur; dst = sm*clip(img+0.5*res,0,1) + (1-sm)*img
template <int LOADM, int STOREM>
__global__ __launch_bounds__(256) void pass_kern(const float* __restrict__ src,
                                                 const float* __restrict__ img,
                                                 const float* res,
                                                 float* __restrict__ dst,
                                                 const float* __restrict__ k1d) {
    __shared__ float lds[CB][LDS_R];
    const int lane = threadIdx.x & 63;
    // force wave id into an SGPR so row indices/addresses scalarize
    const int wvu = __builtin_amdgcn_readfirstlane(threadIdx.x >> 6);
    const int c0 = blockIdx.x * CB;
    const int r0 = blockIdx.y * RB;
    const size_t base = (size_t)blockIdx.z * (IMG * IMG);
    const float* sb = src + base;

    float kern[K];
#pragma unroll
    for (int k = 0; k < K; ++k) kern[k] = k1d[k];  // uniform -> scalar regs

    float acc[VB];
#pragma unroll
    for (int o = 0; o < VB; ++o) acc[o] = 0.f;

    const int rw = r0 + wvu * VB;  // wave's first output row (uniform)

    // sliding window along the slow dim: 82 coalesced loads feed 32 outputs
#pragma unroll
    for (int r = 0; r < NLOOP; ++r) {
        int y = rw - P + r;                      // wave-uniform -> SALU
        const int ya = y < 0 ? -y : y;
        y = min(ya, 2 * IMG - 2 - y);            // reflect; identity in interior
        float v = sb[y * IMG + c0 + lane];
        if (LOADM == 1) v = (fabsf(v) * 255.0f > 10.0f) ? 1.0f : 0.0f;
#pragma unroll
        for (int o = 0; o < VB; ++o) {
            const int k = r - o;
            if (0 <= k && k < K) acc[o] = fmaf(kern[k], v, acc[o]);
        }
    }

    // stage this thread's column into the transpose tile
    // write: addr = lane*129 + row  -> banks (lane + row) % 32, conflict-free
#pragma unroll
    for (int o = 0; o < VB; ++o) lds[lane][wvu * VB + o] = acc[o];
    __syncthreads();

    // transposed, coalesced store (+ fused elementwise epilogue)
    // read: addr = cc*129 + j*64 + lane -> consecutive, conflict-free
#pragma unroll
    for (int i = 0; i < 16; ++i) {
        const int cc = wvu * 16 + i;
#pragma unroll
        for (int j = 0; j < 2; ++j) {
            const float bv = lds[cc][j * 64 + lane];
            const size_t di = base + (size_t)(c0 + cc) * IMG + (r0 + j * 64 + lane);
            if (STOREM == 0) {
                dst[di] = bv;
            } else if (STOREM == 1) {
                dst[di] = img[di] - bv;
            } else {
                const float iv = img[di];
                const float rv = res[di];   // aliases dst: same-index read-then-write only
                float sharp = fmaf(0.5f, rv, iv);
                sharp = fminf(fmaxf(sharp, 0.f), 1.f);
                dst[di] = fmaf(bv, sharp - iv, iv);  // sm*sharp + (1-sm)*img
            }
        }
    }
}

extern "C" void kernel_launch(void* const* d_in, const int* in_sizes, int n_in,
                              void* d_out, int out_size, void* d_ws, size_t ws_size,
                              hipStream_t stream) {
    (void)in_sizes; (void)n_in; (void)out_size; (void)ws_size;
    const float* img = (const float*)d_in[0];
    const float* k1d = (const float*)d_in[1];
    float* out = (float*)d_out;
    float* tmp = (float*)d_ws;  // 48*512*512*4 = 50331648 B scratch

    const dim3 grid(IMG / CB, IMG / RB, NIMG);  // (8, 4, 48)

    pass_kern<0, 0><<<grid, 256, 0, stream>>>(img, nullptr, nullptr, tmp, k1d);
    pass_kern<0, 1><<<grid, 256, 0, stream>>>(tmp, img, nullptr, out, k1d);   // out = residual
    pass_kern<1, 0><<<grid, 256, 0, stream>>>(out, nullptr, nullptr, tmp, k1d);
    pass_kern<0, 2><<<grid, 256, 0, stream>>>(tmp, img, out, out, k1d);       // final, in-place
}

// Round 3
// 120.047 us; speedup vs baseline: 14.4391x; 14.4391x over previous
//
#include <hip/hip_runtime.h>
#include <hip/hip_bf16.h>

// USM sharpen, 48 images of 512x512 f32, 51-tap separable Gaussian, reflect pad.
// One kernel shape for all 4 passes: coalesced loads along fast dim, register
// sliding-window blur along slow dim (VB=16 rows/thread -- 66x16 body, the
// size PROVEN to fully unroll in round 1; VB=32 made the compiler bail and
// spill kern[]/acc[] to scratch), then LDS 64x64 tile transpose on output.
//   pass1: img[y][x]      --vblur--> tmp[x][y]
//   pass2: tmp[x][y]      --xblur--> out[y][x] = img - blur      (residual)
//   pass3: out[y][x] mask --vblur--> tmp[x][y]
//   pass4: tmp[x][y]      --xblur--> out[y][x] = sm*sharp+(1-sm)*img

constexpr int IMG = 512;
constexpr int NIMG = 48;
constexpr int K = 51, P = 25;
constexpr int CB = 64;              // fast-dim columns per block (= lanes)
constexpr int RB = 64;              // slow-dim rows per block (4 waves x VB)
constexpr int VB = 16;              // rows per thread
constexpr int NLOOP = VB + K - 1;   // 66 sliding loads per thread
constexpr int LDS_R = RB + 1;       // stride 65 -> conflict-free both ways

// LOADM: 0 = raw, 1 = mask(|v|*255 > 10)
// STOREM: 0 = blur -> dst (transposed)
//         1 = img - blur -> dst (residual)
//         2 = sm=blur; dst = sm*clip(img+0.5*res,0,1) + (1-sm)*img
template <int LOADM, int STOREM>
__global__ __launch_bounds__(256) void pass_kern(const float* __restrict__ src,
                                                 const float* __restrict__ img,
                                                 const float* res,
                                                 float* __restrict__ dst,
                                                 const float* __restrict__ k1d) {
    __shared__ float lds[CB][LDS_R];
    const int lane = threadIdx.x & 63;
    const int wvu = __builtin_amdgcn_readfirstlane(threadIdx.x >> 6);  // scalarize
    const int c0 = blockIdx.x * CB;
    const int r0 = blockIdx.y * RB;
    const size_t base = (size_t)blockIdx.z * (IMG * IMG);
    const float* sb = src + base;

    float kern[K];
#pragma unroll
    for (int k = 0; k < K; ++k) kern[k] = k1d[k];  // uniform -> scalar regs

    float acc[VB];
#pragma unroll
    for (int o = 0; o < VB; ++o) acc[o] = 0.f;

    const int rw = r0 + wvu * VB;  // wave's first output row (uniform)

    // sliding window along slow dim: 66 coalesced loads feed 16 outputs (816 FMA)
#pragma unroll
    for (int r = 0; r < NLOOP; ++r) {
        int y = rw - P + r;                  // wave-uniform -> SALU
        const int ya = y < 0 ? -y : y;
        y = min(ya, 2 * IMG - 2 - y);        // reflect; identity in interior
        float v = sb[y * IMG + c0 + lane];
        if (LOADM == 1) v = (fabsf(v) * 255.0f > 10.0f) ? 1.0f : 0.0f;
#pragma unroll
        for (int o = 0; o < VB; ++o) {
            const int k = r - o;
            if (0 <= k && k < K) acc[o] = fmaf(kern[k], v, acc[o]);
        }
    }

    // transpose tile: write addr = lane*65 + row -> banks (lane+row)%32, 2-way = free
#pragma unroll
    for (int o = 0; o < VB; ++o) lds[lane][wvu * VB + o] = acc[o];
    __syncthreads();

    // transposed, coalesced store (+ fused elementwise epilogue)
    // read addr = cc*65 + lane -> consecutive -> conflict-free
#pragma unroll
    for (int i = 0; i < 16; ++i) {
        const int cc = wvu * 16 + i;
        const float bv = lds[cc][lane];
        const size_t di = base + (size_t)(c0 + cc) * IMG + (r0 + lane);
        if (STOREM == 0) {
            dst[di] = bv;
        } else if (STOREM == 1) {
            dst[di] = img[di] - bv;
        } else {
            const float iv = img[di];
            const float rv = res[di];   // aliases dst: same-index read-then-write only
            float sharp = fmaf(0.5f, rv, iv);
            sharp = fminf(fmaxf(sharp, 0.f), 1.f);
            dst[di] = fmaf(bv, sharp - iv, iv);  // sm*sharp + (1-sm)*img
        }
    }
}

extern "C" void kernel_launch(void* const* d_in, const int* in_sizes, int n_in,
                              void* d_out, int out_size, void* d_ws, size_t ws_size,
                              hipStream_t stream) {
    (void)in_sizes; (void)n_in; (void)out_size; (void)ws_size;
    const float* img = (const float*)d_in[0];
    const float* k1d = (const float*)d_in[1];
    float* out = (float*)d_out;
    float* tmp = (float*)d_ws;  // 48*512*512*4 = 50331648 B scratch

    const dim3 grid(IMG / CB, IMG / RB, NIMG);  // (8, 8, 48)

    pass_kern<0, 0><<<grid, 256, 0, stream>>>(img, nullptr, nullptr, tmp, k1d);
    pass_kern<0, 1><<<grid, 256, 0, stream>>>(tmp, img, nullptr, out, k1d);   // out = residual
    pass_kern<1, 0><<<grid, 256, 0, stream>>>(out, nullptr, nullptr, tmp, k1d);
    pass_kern<0, 2><<<grid, 256, 0, stream>>>(tmp, img, out, out, k1d);       // final, in-place
}

// Round 4
// 118.020 us; speedup vs baseline: 14.6871x; 1.0172x over previous
//
#include <hip/hip_runtime.h>
#include <hip/hip_bf16.h>

// USM sharpen, 48 images of 512x512 f32, 51-tap separable Gaussian, reflect pad.
// One kernel shape for all 4 passes:
//   1) stage 178 input rows x 64 cols into LDS once per block (coalesced,
//      reflect-padded, optional mask) -- shares halo reads across all 8 waves
//      (load redundancy 4.125x -> 1.39x vs round 3)
//   2) per-thread register sliding-window blur along the slow dim, VB=16
//      (66x16 guarded body -- the PROVEN unrollable size; VB=32 spilled)
//   3) LDS 64x128 transpose tile (reusing the same LDS, acc is in regs across
//      the syncs) -> coalesced transposed store + fused elementwise epilogue
// Pass chain:
//   pass1: img[y][x]      --vblur--> tmp[x][y]
//   pass2: tmp[x][y]      --xblur--> out[y][x] = img - blur      (residual)
//   pass3: out[y][x] mask --vblur--> tmp[x][y]
//   pass4: tmp[x][y]      --xblur--> out[y][x] = sm*sharp+(1-sm)*img

constexpr int IMG = 512;
constexpr int NIMG = 48;
constexpr int K = 51, P = 25;
constexpr int CB = 64;              // fast-dim columns per block (= lanes)
constexpr int RB = 128;             // slow-dim rows per block
constexpr int WAVES = 8;            // 512 threads
constexpr int VB = 16;              // rows per thread (RB / WAVES)
constexpr int NLOOP = VB + K - 1;   // 66 taps+outputs window
constexpr int TR = RB + 2 * P;      // 178 staged input rows
constexpr int TRS = RB + 1;         // transpose tile stride 129 -> conflict-free
constexpr int LDS_FLOATS = TR * CB; // 11392 floats = 45.6 KB (>= 64*129 = 8256)

// LOADM: 0 = raw, 1 = mask(|v|*255 > 10)
// STOREM: 0 = blur -> dst (transposed)
//         1 = img - blur -> dst (residual)
//         2 = sm=blur; dst = sm*clip(img+0.5*res,0,1) + (1-sm)*img
template <int LOADM, int STOREM>
__global__ __launch_bounds__(512) void pass_kern(const float* __restrict__ src,
                                                 const float* __restrict__ img,
                                                 const float* res,
                                                 float* __restrict__ dst,
                                                 const float* __restrict__ k1d) {
    __shared__ float lds[LDS_FLOATS];  // union: in-tile [178][64] / trans [64][129]
    const int lane = threadIdx.x & 63;
    const int wvu = __builtin_amdgcn_readfirstlane(threadIdx.x >> 6);  // scalarize
    const int c0 = blockIdx.x * CB;
    const int r0 = blockIdx.y * RB;
    const size_t base = (size_t)blockIdx.z * (IMG * IMG);
    const float* sb = src + base;

    // ---- stage 178 reflect-padded rows, one 256B coalesced load per row ----
    for (int r = wvu; r < TR; r += WAVES) {
        int y = r0 - P + r;                  // wave-uniform -> SALU
        const int ya = y < 0 ? -y : y;
        y = min(ya, 2 * IMG - 2 - y);        // reflect; identity in interior
        float v = sb[y * IMG + c0 + lane];
        if (LOADM == 1) v = (fabsf(v) * 255.0f > 10.0f) ? 1.0f : 0.0f;
        lds[r * CB + lane] = v;
    }

    float kern[K];
#pragma unroll
    for (int k = 0; k < K; ++k) kern[k] = k1d[k];  // uniform -> scalar regs

    __syncthreads();

    // ---- register sliding window along slow dim, fed from LDS ----
    float acc[VB];
#pragma unroll
    for (int o = 0; o < VB; ++o) acc[o] = 0.f;

    const int trow0 = wvu * VB;  // wave's first tap row in the tile (uniform)
#pragma unroll
    for (int r = 0; r < NLOOP; ++r) {
        const float v = lds[(trow0 + r) * CB + lane];  // uniform row + lane: free
#pragma unroll
        for (int o = 0; o < VB; ++o) {
            const int k = r - o;
            if (0 <= k && k < K) acc[o] = fmaf(kern[k], v, acc[o]);
        }
    }

    __syncthreads();  // input tile fully consumed; safe to overwrite (union)

    // ---- transpose tile: write addr = lane*129 + row -> 2-way alias = free ----
#pragma unroll
    for (int o = 0; o < VB; ++o) lds[lane * TRS + trow0 + o] = acc[o];
    __syncthreads();

    // ---- transposed coalesced store + fused epilogue ----
#pragma unroll
    for (int i = 0; i < 8; ++i) {
        const int cc = wvu * 8 + i;
#pragma unroll
        for (int j = 0; j < 2; ++j) {
            const int rr = j * 64 + lane;
            const float bv = lds[cc * TRS + rr];
            const size_t di = base + (size_t)(c0 + cc) * IMG + (r0 + rr);
            if (STOREM == 0) {
                dst[di] = bv;
            } else if (STOREM == 1) {
                dst[di] = img[di] - bv;
            } else {
                const float iv = img[di];
                const float rv = res[di];   // aliases dst: same-index RMW only
                float sharp = fmaf(0.5f, rv, iv);
                sharp = fminf(fmaxf(sharp, 0.f), 1.f);
                dst[di] = fmaf(bv, sharp - iv, iv);  // sm*sharp + (1-sm)*img
            }
        }
    }
}

extern "C" void kernel_launch(void* const* d_in, const int* in_sizes, int n_in,
                              void* d_out, int out_size, void* d_ws, size_t ws_size,
                              hipStream_t stream) {
    (void)in_sizes; (void)n_in; (void)out_size; (void)ws_size;
    const float* img = (const float*)d_in[0];
    const float* k1d = (const float*)d_in[1];
    float* out = (float*)d_out;
    float* tmp = (float*)d_ws;  // 48*512*512*4 = 50331648 B scratch

    const dim3 grid(IMG / CB, IMG / RB, NIMG);  // (8, 4, 48) = 1536 blocks

    pass_kern<0, 0><<<grid, 512, 0, stream>>>(img, nullptr, nullptr, tmp, k1d);
    pass_kern<0, 1><<<grid, 512, 0, stream>>>(tmp, img, nullptr, out, k1d);   // out = residual
    pass_kern<1, 0><<<grid, 512, 0, stream>>>(out, nullptr, nullptr, tmp, k1d);
    pass_kern<0, 2><<<grid, 512, 0, stream>>>(tmp, img, out, out, k1d);       // final, in-place
}

// Round 5
// 100.919 us; speedup vs baseline: 17.1758x; 1.1695x over previous
//
#include <hip/hip_runtime.h>
#include <hip/hip_bf16.h>

// USM sharpen, 48 images of 512x512 f32, 51-tap separable Gaussian, reflect pad.
// Round-4 structure (LDS row staging + VB=16 register sliding window + LDS
// transpose tile) with ALL intermediates in bf16 to cut HBM/L2 traffic:
//   pass1: img  f32[y][x] --vblur--> vb  bf16[x][y]   (ws slot 0)
//   pass2: vb  bf16[x][y] --xblur--> res bf16[y][x] = img - blur  (ws slot 1)
//   pass3: res bf16[y][x] --mask+vblur--> vb bf16[x][y]           (slot 0 reuse)
//   pass4: vb  bf16[x][y] --xblur--> out f32[y][x] = sm*sharp+(1-sm)*img
// ws usage: 2 * 48*512*512*2 B = 50331648 B (same budget as prior rounds).
// Working set img(50)+vb(25)+res(25) = 100 MB < 256 MB L3.

constexpr int IMG = 512;
constexpr int NIMG = 48;
constexpr int K = 51, P = 25;
constexpr int CB = 64;              // fast-dim columns per block (= lanes)
constexpr int RB = 128;             // slow-dim rows per block
constexpr int WAVES = 8;            // 512 threads
constexpr int VB = 16;              // rows per thread (proven unrollable; 32 spills)
constexpr int NLOOP = VB + K - 1;   // 66
constexpr int TR = RB + 2 * P;      // 178 staged input rows
constexpr int TRS = RB + 1;         // transpose tile stride 129 -> conflict-free
constexpr int LDS_FLOATS = TR * CB; // 45.6 KB (>= 64*129 for the union)

__device__ __forceinline__ float bf2f(unsigned short u) {
    unsigned int x = (unsigned int)u << 16;
    return __builtin_bit_cast(float, x);
}
__device__ __forceinline__ unsigned short f2bf(float f) {
    unsigned int u = __builtin_bit_cast(unsigned int, f);
    u += 0x7FFF + ((u >> 16) & 1);  // round-to-nearest-even (finite inputs only)
    return (unsigned short)(u >> 16);
}

// SRCB: src element type 0=f32, 1=bf16
// LOADM: 1 = apply mask(|v|*255 > 10) at stage time
// STOREM: 0 = blur -> dst bf16 (transposed)
//         1 = img - blur -> dst bf16 (residual)
//         2 = sm=blur; dst f32 = img + sm*(clip(img+0.5*res,0,1) - img)
template <int SRCB, int LOADM, int STOREM>
__global__ __launch_bounds__(512) void pass_kern(const void* __restrict__ srcv,
                                                 const float* __restrict__ img,
                                                 const unsigned short* __restrict__ res,
                                                 void* __restrict__ dstv,
                                                 const float* __restrict__ k1d) {
    __shared__ float lds[LDS_FLOATS];  // union: stage [178][64] / transpose [64][129]
    const int lane = threadIdx.x & 63;
    const int wvu = __builtin_amdgcn_readfirstlane(threadIdx.x >> 6);  // scalarize
    const int c0 = blockIdx.x * CB;
    const int r0 = blockIdx.y * RB;
    const size_t base = (size_t)blockIdx.z * (IMG * IMG);

    // ---- stage 178 reflect-padded rows (coalesced; optional mask transform) ----
    for (int r = wvu; r < TR; r += WAVES) {
        int y = r0 - P + r;                  // wave-uniform -> SALU
        const int ya = y < 0 ? -y : y;
        y = min(ya, 2 * IMG - 2 - y);        // reflect; identity in interior
        const size_t si = base + (size_t)y * IMG + c0 + lane;
        float v = SRCB ? bf2f(((const unsigned short*)srcv)[si])
                       : ((const float*)srcv)[si];
        if (LOADM == 1) v = (fabsf(v) * 255.0f > 10.0f) ? 1.0f : 0.0f;
        lds[r * CB + lane] = v;
    }

    float kern[K];
#pragma unroll
    for (int k = 0; k < K; ++k) kern[k] = k1d[k];  // uniform -> scalar regs

    __syncthreads();

    // ---- register sliding window along slow dim, fed from LDS ----
    float acc[VB];
#pragma unroll
    for (int o = 0; o < VB; ++o) acc[o] = 0.f;

    const int trow0 = wvu * VB;
#pragma unroll
    for (int r = 0; r < NLOOP; ++r) {
        const float v = lds[(trow0 + r) * CB + lane];  // uniform row: 2-way alias, free
#pragma unroll
        for (int o = 0; o < VB; ++o) {
            const int k = r - o;
            if (0 <= k && k < K) acc[o] = fmaf(kern[k], v, acc[o]);
        }
    }

    __syncthreads();  // input tile consumed; safe to overwrite (union)

    // ---- transpose tile: write addr = lane*129 + row -> conflict-free ----
#pragma unroll
    for (int o = 0; o < VB; ++o) lds[lane * TRS + trow0 + o] = acc[o];
    __syncthreads();

    // ---- transposed coalesced store + fused epilogue ----
#pragma unroll
    for (int i = 0; i < 8; ++i) {
        const int cc = wvu * 8 + i;
#pragma unroll
        for (int j = 0; j < 2; ++j) {
            const int rr = j * 64 + lane;
            const float bv = lds[cc * TRS + rr];
            const size_t di = base + (size_t)(c0 + cc) * IMG + (r0 + rr);
            if (STOREM == 0) {
                ((unsigned short*)dstv)[di] = f2bf(bv);
            } else if (STOREM == 1) {
                ((unsigned short*)dstv)[di] = f2bf(img[di] - bv);
            } else {
                const float iv = img[di];
                const float rv = bf2f(res[di]);
                float sharp = fmaf(0.5f, rv, iv);
                sharp = fminf(fmaxf(sharp, 0.f), 1.f);
                ((float*)dstv)[di] = fmaf(bv, sharp - iv, iv);  // img + sm*(sharp-img)
            }
        }
    }
}

extern "C" void kernel_launch(void* const* d_in, const int* in_sizes, int n_in,
                              void* d_out, int out_size, void* d_ws, size_t ws_size,
                              hipStream_t stream) {
    (void)in_sizes; (void)n_in; (void)out_size; (void)ws_size;
    const float* img = (const float*)d_in[0];
    const float* k1d = (const float*)d_in[1];
    float* out = (float*)d_out;
    unsigned short* vb = (unsigned short*)d_ws;                             // 25165824 B
    unsigned short* rs = (unsigned short*)d_ws + (size_t)NIMG * IMG * IMG;  // 25165824 B

    const dim3 grid(IMG / CB, IMG / RB, NIMG);  // (8, 4, 48) = 1536 blocks

    pass_kern<0, 0, 0><<<grid, 512, 0, stream>>>(img, nullptr, nullptr, vb, k1d);
    pass_kern<1, 0, 1><<<grid, 512, 0, stream>>>(vb, img, nullptr, rs, k1d);   // rs = residual
    pass_kern<1, 1, 0><<<grid, 512, 0, stream>>>(rs, nullptr, nullptr, vb, k1d);
    pass_kern<1, 0, 2><<<grid, 512, 0, stream>>>(vb, img, rs, out, k1d);       // final
}